// Round 1
// baseline (744.327 us; speedup 1.0000x reference)
//
#include <hip/hip_runtime.h>
#include <hip/hip_bf16.h>

#define H 256
#define W 256
#define CIN 128
#define COUT 128
#define BATCH 8
#define LDA 136  // LDS row stride in bf16 elements (128 + 8 pad, keeps 16B align)

typedef float f32x4 __attribute__((ext_vector_type(4)));
typedef short bf16x8 __attribute__((ext_vector_type(8)));

static __device__ __forceinline__ unsigned short f2bf(float f) {
    unsigned int x = __float_as_uint(f);
    unsigned int r = (x + 0x7fffu + ((x >> 16) & 1u)) >> 16;
    return (unsigned short)r;
}

// ---------------------------------------------------------------------------
// Kernel 1: style modulation + demod + pre-swizzle weights into MFMA B-frag
// order. Single block, 1024 threads, all fp32 math (exact vs reference).
// Output layout (bf16): unit u = ((kk*4 + kc)*8 + ntile)*64 + lane, each unit
// 8 bf16 = B[k = kc*32 + (lane>>4)*8 + j][n = ntile*16 + (lane&15)], kk=kh*3+kw
// ---------------------------------------------------------------------------
__global__ __launch_bounds__(1024) void prep_kernel(
    const float* __restrict__ style, const float* __restrict__ kern,
    const float* __restrict__ w_mod, const float* __restrict__ b_mod,
    unsigned short* __restrict__ wprep)
{
    __shared__ float sbuf[1024];
    __shared__ float scaleArr[CIN];
    __shared__ float dArr[COUT];
    const int t = threadIdx.x;
    const int b = t >> 7;
    const int c = t & 127;

    // ---- s = style @ w_mod + b_mod + 1  (each thread: one [b][c]) ----
    float acc = 0.f;
    const float4* st4 = (const float4*)(style + b * 512);
    for (int k4 = 0; k4 < 128; ++k4) {
        float4 s4 = st4[k4];
        int k = k4 * 4;
        acc += s4.x * w_mod[(k + 0) * CIN + c];
        acc += s4.y * w_mod[(k + 1) * CIN + c];
        acc += s4.z * w_mod[(k + 2) * CIN + c];
        acc += s4.w * w_mod[(k + 3) * CIN + c];
    }
    float sval = acc + b_mod[c] + 1.0f;

    // ---- global max-abs over all 1024 s values ----
    sbuf[t] = fabsf(sval);
    __syncthreads();
    for (int off = 512; off > 0; off >>= 1) {
        if (t < off) sbuf[t] = fmaxf(sbuf[t], sbuf[t + off]);
        __syncthreads();
    }
    float invmax = 1.0f / sbuf[0];
    const float he_std = 1.0f / sqrtf(1152.0f);
    if (t < CIN) scaleArr[t] = sval * invmax * he_std;  // b==0 threads: s[0][c]
    __syncthreads();

    // ---- per-cout demod: d = rsqrt(sum_k (kernel*scale)^2 + 1e-8) ----
    {
        const int co = t & 127;
        const int slice = t >> 7;  // 8 slices of 144 over the 1152 k values
        float ss = 0.f;
        for (int j = 0; j < 144; ++j) {
            int i = slice * 144 + j;     // i = khkw*128 + ci
            int ci = i & 127;
            float wv = kern[i * 128 + co] * scaleArr[ci];
            ss += wv * wv;
        }
        sbuf[t] = ss;
        __syncthreads();
        if (t < 128) {
            float sum = 0.f;
            for (int sl = 0; sl < 8; ++sl) sum += sbuf[sl * 128 + t];
            dArr[t] = rsqrtf(sum + 1e-8f);
        }
        __syncthreads();
    }

    // ---- write pre-swizzled bf16 B-fragments ----
    for (int u = t; u < 9 * 4 * 8 * 64; u += 1024) {
        int lane  = u & 63;
        int ntile = (u >> 6) & 7;
        int kc    = (u >> 9) & 3;
        int kk    = u >> 11;
        int co  = ntile * 16 + (lane & 15);
        int cib = kc * 32 + (lane >> 4) * 8;
        float dv = dArr[co];
        unsigned int packed[4];
        for (int jp = 0; jp < 4; ++jp) {
            int ci0 = cib + jp * 2;
            float w0 = kern[(kk * 128 + ci0)     * 128 + co] * scaleArr[ci0]     * dv;
            float w1 = kern[(kk * 128 + ci0 + 1) * 128 + co] * scaleArr[ci0 + 1] * dv;
            packed[jp] = (unsigned int)f2bf(w0) | ((unsigned int)f2bf(w1) << 16);
        }
        ((uint4*)wprep)[u] = make_uint4(packed[0], packed[1], packed[2], packed[3]);
    }
}

// ---------------------------------------------------------------------------
// Kernel 2: implicit-GEMM conv. Block = 128 pixels (one image row segment)
// x 128 couts; 4 waves in 2x2, each wave 64x64 via 4x4 mfma_f32_16x16x32_bf16.
// Per kh: stage halo row (130 px x 128 cin, fp32->bf16) into LDS once; 3 kw
// positions read shifted windows. B-frags loaded from L2-resident wprep.
// ---------------------------------------------------------------------------
__global__ __launch_bounds__(256) void conv_kernel(
    const float* __restrict__ x, const unsigned short* __restrict__ wprep,
    const float* __restrict__ noise_strength, const float* __restrict__ bias,
    const float* __restrict__ noise, float* __restrict__ out)
{
    __shared__ unsigned short ldsA[130 * LDA];
    const int tid  = threadIdx.x;
    const int lane = tid & 63;
    const int wave = tid >> 6;
    const int wm = wave & 1;   // wave row (pixels)
    const int wn = wave >> 1;  // wave col (couts)
    const int wt = blockIdx.x;        // 0..1 (w tile)
    const int h  = blockIdx.y;        // 0..255
    const int b  = blockIdx.z;        // 0..7
    const int wstart = wt * 128;

    f32x4 acc[4][4];
    const f32x4 zero = {0.f, 0.f, 0.f, 0.f};
    for (int i = 0; i < 4; ++i)
        for (int j = 0; j < 4; ++j) acc[i][j] = zero;

    for (int kh = 0; kh < 3; ++kh) {
        __syncthreads();  // protect LDS from previous iteration's readers
        const int hImg = h + kh - 1;
        const bool rowValid = (hImg >= 0) && (hImg < H);
        const float* rowPtr = x + ((size_t)(b * H + hImg) * W) * CIN;
        for (int idx = tid; idx < 130 * 32; idx += 256) {
            int p  = idx >> 5;       // halo pixel 0..129  (w = wstart-1+p)
            int c4 = idx & 31;       // float4 index in cin
            int wImg = wstart - 1 + p;
            float4 v = make_float4(0.f, 0.f, 0.f, 0.f);
            if (rowValid && (unsigned)wImg < (unsigned)W)
                v = *(const float4*)(rowPtr + (size_t)wImg * CIN + c4 * 4);
            ushort4 u;
            u.x = f2bf(v.x); u.y = f2bf(v.y); u.z = f2bf(v.z); u.w = f2bf(v.w);
            *(ushort4*)&ldsA[p * LDA + c4 * 4] = u;
        }
        __syncthreads();

        #pragma unroll
        for (int kw = 0; kw < 3; ++kw) {
            const int kk = kh * 3 + kw;
            #pragma unroll
            for (int kc = 0; kc < 4; ++kc) {
                bf16x8 bfrag[4], afrag[4];
                const bf16x8* bptr = (const bf16x8*)wprep +
                                     (((kk * 4 + kc) * 8 + wn * 4) * 64 + lane);
                #pragma unroll
                for (int j = 0; j < 4; ++j) bfrag[j] = bptr[j * 64];
                const int ka = kc * 32 + (lane >> 4) * 8;
                #pragma unroll
                for (int i = 0; i < 4; ++i) {
                    int m = wm * 64 + i * 16 + (lane & 15) + kw;  // halo row index
                    afrag[i] = *(const bf16x8*)&ldsA[m * LDA + ka];
                }
                #pragma unroll
                for (int i = 0; i < 4; ++i)
                    #pragma unroll
                    for (int j = 0; j < 4; ++j)
                        acc[i][j] = __builtin_amdgcn_mfma_f32_16x16x32_bf16(
                            afrag[i], bfrag[j], acc[i][j], 0, 0, 0);
            }
        }
    }

    // ---- epilogue: noise + bias + lrelu(0.2)*sqrt(2) ----
    const float ns  = noise_strength[0] * 0.5f;
    const float RT2 = 1.41421356237309515f;
    const size_t pixBase = ((size_t)(b * H + h) * W) + wstart;
    #pragma unroll
    for (int i = 0; i < 4; ++i) {
        const int mbase = wm * 64 + i * 16 + ((lane >> 4) << 2);
        #pragma unroll
        for (int r = 0; r < 4; ++r) {
            const size_t pix = pixBase + (mbase + r);
            const float nz = noise[pix] * ns;
            #pragma unroll
            for (int j = 0; j < 4; ++j) {
                const int col = wn * 64 + j * 16 + (lane & 15);
                float v = acc[i][j][r] + nz + bias[col];
                v = (v >= 0.f ? v : 0.2f * v) * RT2;
                out[pix * COUT + col] = v;
            }
        }
    }
}

extern "C" void kernel_launch(void* const* d_in, const int* in_sizes, int n_in,
                              void* d_out, int out_size, void* d_ws, size_t ws_size,
                              hipStream_t stream) {
    const float* x              = (const float*)d_in[0];
    const float* style          = (const float*)d_in[1];
    const float* kern           = (const float*)d_in[2];
    const float* w_mod          = (const float*)d_in[3];
    const float* b_mod          = (const float*)d_in[4];
    const float* noise_strength = (const float*)d_in[5];
    const float* bias           = (const float*)d_in[6];
    const float* noise          = (const float*)d_in[7];
    float* out = (float*)d_out;
    unsigned short* wprep = (unsigned short*)d_ws;  // 294,912 B of scratch

    hipLaunchKernelGGL(prep_kernel, dim3(1), dim3(1024), 0, stream,
                       style, kern, w_mod, b_mod, wprep);
    hipLaunchKernelGGL(conv_kernel, dim3(2, 256, 8), dim3(256), 0, stream,
                       x, wprep, noise_strength, bias, noise, out);
}